// Round 1
// 613.168 us; speedup vs baseline: 1.0388x; 1.0388x over previous
//
#include <hip/hip_runtime.h>
#include <math.h>

#define D 256
#define EPSV 1e-8f
#define GAMMAV 0.2f
#define SCAN_B 256

__device__ __forceinline__ float cleanf(float x) {
    if (isnan(x)) return 0.0f;
    if (isinf(x)) return x > 0.0f ? 10000.0f : 0.0001f;
    return x;
}

// bf16 <-> f32 (RNE on the way down; exact on the way up)
__device__ __forceinline__ unsigned short f2bf(float x) {
    unsigned u = __float_as_uint(x);
    return (unsigned short)((u + 0x7FFFu + ((u >> 16) & 1u)) >> 16);
}
__device__ __forceinline__ float bf2f(unsigned short b) {
    return __uint_as_float(((unsigned)b) << 16);
}

// ---- fused: fp32->bf16 table convert + counting + omega denominator ---
// blocks [0, nbc)        : convert entity_emb fp32 -> bf16
// blocks [nbc, nbc+eb)   : degree counts + omega segment-sum (atomics)
// The two halves are independent; fusing lets the atomic-heavy half
// overlap the streaming-BW half instead of serializing.

__global__ __launch_bounds__(256) void k_pre(
    const float4* __restrict__ ein, ushort4* __restrict__ eout, int n4, int nbc,
    const int* __restrict__ head, const float* __restrict__ omega,
    const int* __restrict__ iu,
    int* __restrict__ counts_e, int* __restrict__ counts_u,
    float* __restrict__ denom, int E, int IE) {
    if ((int)blockIdx.x < nbc) {
        int i = blockIdx.x * 256 + threadIdx.x;
        if (i < n4) {
            float4 v = ein[i];
            eout[i] = make_ushort4(f2bf(v.x), f2bf(v.y), f2bf(v.z), f2bf(v.w));
        }
    } else {
        int i = (blockIdx.x - nbc) * 256 + threadIdx.x;
        if (i < E) {
            int h = head[i];
            atomicAdd(&counts_e[h], 1);
            atomicAdd(&denom[h], omega[i]);
        } else if (i < E + IE) {
            atomicAdd(&counts_u[iu[i - E]], 1);
        }
    }
}

// ---- hierarchical exclusive scan (both arrays, one launch set) --------

__global__ __launch_bounds__(SCAN_B) void k_scan1(
    const int* __restrict__ ce, int* __restrict__ oe, int* __restrict__ be,
    int nE, int nbE,
    const int* __restrict__ cu, int* __restrict__ ou, int* __restrict__ bu,
    int nU) {
    __shared__ int tmp[SCAN_B];
    const int* in; int* out; int* bs; int n; int lb;
    if ((int)blockIdx.x < nbE) { in = ce; out = oe; bs = be; n = nE; lb = blockIdx.x; }
    else { in = cu; out = ou; bs = bu; n = nU; lb = blockIdx.x - nbE; }
    int i = lb * SCAN_B + threadIdx.x;
    int v = (i < n) ? in[i] : 0;
    tmp[threadIdx.x] = v;
    __syncthreads();
    for (int o = 1; o < SCAN_B; o <<= 1) {
        int t = (threadIdx.x >= (unsigned)o) ? tmp[threadIdx.x - o] : 0;
        __syncthreads();
        tmp[threadIdx.x] += t;
        __syncthreads();
    }
    if (i < n) out[i] = tmp[threadIdx.x] - v;   // exclusive
    if (threadIdx.x == SCAN_B - 1) bs[lb] = tmp[threadIdx.x];
}

__global__ __launch_bounds__(1024) void k_scan2(
    int* __restrict__ be, int nbE, int* __restrict__ bu, int nbU) {
    __shared__ int tmp[1024];
    int* bs = (blockIdx.x == 0) ? be : bu;
    int nb  = (blockIdx.x == 0) ? nbE : nbU;
    int v = ((int)threadIdx.x < nb) ? bs[threadIdx.x] : 0;
    tmp[threadIdx.x] = v;
    __syncthreads();
    for (int o = 1; o < 1024; o <<= 1) {
        int t = (threadIdx.x >= (unsigned)o) ? tmp[threadIdx.x - o] : 0;
        __syncthreads();
        tmp[threadIdx.x] += t;
        __syncthreads();
    }
    if ((int)threadIdx.x < nb) bs[threadIdx.x] = tmp[threadIdx.x] - v;  // exclusive
}

__global__ __launch_bounds__(SCAN_B) void k_scan3(
    int* __restrict__ oe, int* __restrict__ cure, const int* __restrict__ be,
    int nE, int nbE,
    int* __restrict__ ou, int* __restrict__ curu, const int* __restrict__ bu,
    int nU) {
    int* out; int* cur; const int* bs; int n; int lb;
    if ((int)blockIdx.x < nbE) { out = oe; cur = cure; bs = be; n = nE; lb = blockIdx.x; }
    else { out = ou; cur = curu; bs = bu; n = nU; lb = blockIdx.x - nbE; }
    int i = lb * SCAN_B + threadIdx.x;
    if (i < n) {
        int v = out[i] + bs[lb];
        out[i] = v;
        cur[i] = v;
    }
}

// ---- CSR fill: packed meta + inline alpha + eta denominator -----------

__global__ __launch_bounds__(256) void k_fill_both(
    const int* __restrict__ head, const int* __restrict__ tail,
    const int* __restrict__ etype, const float* __restrict__ omega,
    const int* __restrict__ iu, const int* __restrict__ ii,
    const float* __restrict__ iw,
    const float* __restrict__ denom, float* __restrict__ denom2,
    int* __restrict__ cursor_e, int* __restrict__ cursor_u,
    int2* __restrict__ kg, int2* __restrict__ uc, int E, int IE) {
    int i = blockIdx.x * blockDim.x + threadIdx.x;
    if (i < E) {
        int h = head[i];
        float a = omega[i] / (denom[h] + EPSV);
        int p = atomicAdd(&cursor_e[h], 1);
        int2 m;
        m.x = tail[i] | ((etype[i] - 1) << 20);   // tail < 2^20, rel < 2^5
        m.y = __float_as_int(a);
        kg[p] = m;
        if (a > GAMMAV) atomicAdd(&denom2[h], a);
    } else if (i < E + IE) {
        int e = i - E;
        int u = iu[e];
        int p = atomicAdd(&cursor_u[u], 1);
        int2 m;
        m.x = ii[e];
        m.y = __float_as_int(iw[e]);
        uc[p] = m;
    }
}

// ---- fused hop: ent gather + usr gather in one dispatch ----------------
// waves [0, n_ent)            : entity rows (bf16 src -> bf16 dst, hop3 fp32 res)
// waves [n_ent, n_ent+n_users): user rows   (bf16 src -> fp32 usr_res RMW)
// Edge loop is batched x4: 4 metas loaded up front, then 8 independent
// VMEM loads (4 row gathers + 4 rel rows) issued before any use -> 4x the
// memory-level parallelism of the previous one-edge-at-a-time loop.
// Tail edges are clamped to end-1 with weight 0 (dup loads are cache hits).

__global__ __launch_bounds__(256) void k_hop(
    const int* __restrict__ offs_e, const int* __restrict__ cnt_e,
    const int2* __restrict__ kg,
    const int* __restrict__ offs_u, const int* __restrict__ cnt_u,
    const int2* __restrict__ uc,
    const float* __restrict__ denom2,
    const float* __restrict__ rel,              // fp32 (tiny, cached)
    const unsigned short* __restrict__ src,     // bf16 entity features
    const unsigned short* __restrict__ ent0b,   // bf16 entity_emb (hop3)
    const unsigned short* __restrict__ y1b,     // bf16 hop-1 output (hop3)
    const unsigned short* __restrict__ y2b,     // bf16 hop-2 output (hop3)
    unsigned short* __restrict__ ent_out_b,     // bf16 dst (hops 1,2)
    float* __restrict__ ent_res,                // fp32 dst (hop3)
    const float* __restrict__ user0,
    float* __restrict__ usr_res,
    int n_ent, int n_users, int hop) {
    int row  = (int)((blockIdx.x * (size_t)blockDim.x + threadIdx.x) >> 6);
    int lane = threadIdx.x & 63;
    if (row < n_ent) {
        int s = offs_e[row], deg = cnt_e[row];
        int end = s + deg;
        const bool eta = (hop == 3);
        float den2i = 0.0f;
        if (eta) den2i = 1.0f / (denom2[row] + EPSV);
        float4 acc = make_float4(0.f, 0.f, 0.f, 0.f);
        for (int j = s; j < end; j += 4) {
            int e1 = end - 1;
            int2 mm[4];
            #pragma unroll
            for (int k = 0; k < 4; ++k) {
                int jj = j + k;
                mm[k] = kg[jj < end ? jj : e1];
            }
            ushort4 eb[4];
            float4  rw[4];
            float   rv[4];
            #pragma unroll
            for (int k = 0; k < 4; ++k) {
                int t = mm[k].x & 0xFFFFF;
                int r = ((unsigned)mm[k].x) >> 20;
                float a = __int_as_float(mm[k].y);
                float x = a;
                if (eta) x = (a > GAMMAV) ? a * den2i : 0.0f;
                rv[k] = (j + k < end) ? x : 0.0f;
                eb[k] = ((const ushort4*)(src + (size_t)t * D))[lane];
                rw[k] = ((const float4*)(rel + (size_t)r * D))[lane];
            }
            #pragma unroll
            for (int k = 0; k < 4; ++k) {
                acc.x += rv[k] * bf2f(eb[k].x) * rw[k].x;
                acc.y += rv[k] * bf2f(eb[k].y) * rw[k].y;
                acc.z += rv[k] * bf2f(eb[k].z) * rw[k].z;
                acc.w += rv[k] * bf2f(eb[k].w) * rw[k].w;
            }
        }
        float cinv = 1.0f / ((deg > 0) ? (float)deg : 1.0f);
        acc.x *= cinv; acc.y *= cinv; acc.z *= cinv; acc.w *= cinv;
        float ss = acc.x * acc.x + acc.y * acc.y + acc.z * acc.z + acc.w * acc.w;
        #pragma unroll
        for (int o = 32; o >= 1; o >>= 1) ss += __shfl_down(ss, o);
        ss = __shfl(ss, 0);
        float nrm = sqrtf(ss);
        float dninv = 1.0f / ((nrm > EPSV) ? nrm : EPSV);
        float4 y;
        y.x = cleanf(acc.x * dninv);
        y.y = cleanf(acc.y * dninv);
        y.z = cleanf(acc.z * dninv);
        y.w = cleanf(acc.w * dninv);
        if (hop == 3) {
            ushort4 a0 = ((const ushort4*)(ent0b + (size_t)row * D))[lane];
            ushort4 a1 = ((const ushort4*)(y1b  + (size_t)row * D))[lane];
            ushort4 a2 = ((const ushort4*)(y2b  + (size_t)row * D))[lane];
            y.x += bf2f(a0.x) + bf2f(a1.x) + bf2f(a2.x);
            y.y += bf2f(a0.y) + bf2f(a1.y) + bf2f(a2.y);
            y.z += bf2f(a0.z) + bf2f(a1.z) + bf2f(a2.z);
            y.w += bf2f(a0.w) + bf2f(a1.w) + bf2f(a2.w);
            ((float4*)(ent_res + (size_t)row * D))[lane] = y;
        } else {
            ((ushort4*)(ent_out_b + (size_t)row * D))[lane] =
                make_ushort4(f2bf(y.x), f2bf(y.y), f2bf(y.z), f2bf(y.w));
        }
    } else {
        int u = row - n_ent;
        if (u >= n_users) return;
        int s = offs_u[u], deg = cnt_u[u];
        int end = s + deg;
        float4 acc = make_float4(0.f, 0.f, 0.f, 0.f);
        for (int j = s; j < end; j += 4) {
            int e1 = end - 1;
            int2 mm[4];
            #pragma unroll
            for (int k = 0; k < 4; ++k) {
                int jj = j + k;
                mm[k] = uc[jj < end ? jj : e1];
            }
            ushort4 eb[4];
            float   wv[4];
            #pragma unroll
            for (int k = 0; k < 4; ++k) {
                wv[k] = (j + k < end) ? __int_as_float(mm[k].y) : 0.0f;
                eb[k] = ((const ushort4*)(src + (size_t)mm[k].x * D))[lane];
            }
            #pragma unroll
            for (int k = 0; k < 4; ++k) {
                acc.x += wv[k] * bf2f(eb[k].x);
                acc.y += wv[k] * bf2f(eb[k].y);
                acc.z += wv[k] * bf2f(eb[k].z);
                acc.w += wv[k] * bf2f(eb[k].w);
            }
        }
        float ss = acc.x * acc.x + acc.y * acc.y + acc.z * acc.z + acc.w * acc.w;
        #pragma unroll
        for (int o = 32; o >= 1; o >>= 1) ss += __shfl_down(ss, o);
        ss = __shfl(ss, 0);
        float nrm = sqrtf(ss);
        float dninv = 1.0f / ((nrm > EPSV) ? nrm : EPSV);
        float4 y;
        y.x = cleanf(acc.x * dninv);
        y.y = cleanf(acc.y * dninv);
        y.z = cleanf(acc.z * dninv);
        y.w = cleanf(acc.w * dninv);
        float4 base;
        if (hop == 1) base = ((const float4*)(user0 + (size_t)u * D))[lane];
        else          base = ((const float4*)(usr_res + (size_t)u * D))[lane];
        y.x += base.x; y.y += base.y; y.z += base.z; y.w += base.w;
        ((float4*)(usr_res + (size_t)u * D))[lane] = y;
    }
}

extern "C" void kernel_launch(void* const* d_in, const int* in_sizes, int n_in,
                              void* d_out, int out_size, void* d_ws, size_t ws_size,
                              hipStream_t stream) {
    const float* user_emb   = (const float*)d_in[0];
    const float* entity_emb = (const float*)d_in[1];
    const int*   edge_index = (const int*)d_in[2];
    const int*   edge_type  = (const int*)d_in[3];
    const float* omega      = (const float*)d_in[4];
    const int*   inter_edge = (const int*)d_in[5];
    const float* inter_w    = (const float*)d_in[6];
    const float* rel_emb    = (const float*)d_in[7];

    const int n_users = in_sizes[0] / D;
    const int n_ent   = in_sizes[1] / D;
    const int E       = in_sizes[3];
    const int IE      = in_sizes[6];

    const int* head = edge_index;
    const int* tail = edge_index + E;
    const int* iu   = inter_edge;
    const int* ii   = inter_edge + IE;

    // ---- workspace layout ----
    char* w = (char*)d_ws;
    size_t entBh = (size_t)n_ent * D * sizeof(unsigned short);   // bf16 table
    unsigned short* ent0b = (unsigned short*)w;  w += entBh;
    unsigned short* ent_a = (unsigned short*)w;  w += entBh;
    unsigned short* ent_b = (unsigned short*)w;  w += entBh;
    int2*  kg    = (int2*)w;   w += (size_t)E * sizeof(int2);
    int2*  ucsr  = (int2*)w;   w += (size_t)IE * sizeof(int2);
    // zero-init region: counts_e | counts_u | denom | denom2 (contiguous)
    int*   counts_e = (int*)w;   w += (size_t)n_ent * sizeof(int);
    int*   counts_u = (int*)w;   w += (size_t)n_users * sizeof(int);
    float* denom    = (float*)w; w += (size_t)n_ent * sizeof(float);
    float* denom2   = (float*)w; w += (size_t)n_ent * sizeof(float);
    size_t zeroB = ((size_t)n_ent * 3 + n_users) * sizeof(int);
    int*   offs_e   = (int*)w; w += (size_t)n_ent * sizeof(int);
    int*   offs_u   = (int*)w; w += (size_t)n_users * sizeof(int);
    int*   cursor_e = (int*)w; w += (size_t)n_ent * sizeof(int);
    int*   cursor_u = (int*)w; w += (size_t)n_users * sizeof(int);
    int*   bsums_e  = (int*)w; w += 1024 * sizeof(int);
    int*   bsums_u  = (int*)w; w += 1024 * sizeof(int);

    float* ent_res = (float*)d_out;
    float* usr_res = (float*)d_out + (size_t)n_ent * D;

    hipMemsetAsync(counts_e, 0, zeroB, stream);

    // ---- fused: bf16 convert + counts + omega denominators ----
    int n4  = n_ent * (D / 4);
    int nbc = (n4 + 255) / 256;
    int total_edges = E + IE;
    int eb = (total_edges + 255) / 256;
    k_pre<<<nbc + eb, 256, 0, stream>>>(
        (const float4*)entity_emb, (ushort4*)ent0b, n4, nbc,
        head, omega, iu, counts_e, counts_u, denom, E, IE);

    // ---- exclusive scans -> offsets (+cursors) ----
    int nbE = (n_ent + SCAN_B - 1) / SCAN_B;
    int nbU = (n_users + SCAN_B - 1) / SCAN_B;
    k_scan1<<<nbE + nbU, SCAN_B, 0, stream>>>(counts_e, offs_e, bsums_e, n_ent, nbE,
                                              counts_u, offs_u, bsums_u, n_users);
    k_scan2<<<2, 1024, 0, stream>>>(bsums_e, nbE, bsums_u, nbU);
    k_scan3<<<nbE + nbU, SCAN_B, 0, stream>>>(offs_e, cursor_e, bsums_e, n_ent, nbE,
                                              offs_u, cursor_u, bsums_u, n_users);

    // ---- fill CSR (packed, alpha inline, eta denominator) ----
    k_fill_both<<<eb, 256, 0, stream>>>(head, tail, edge_type, omega, iu, ii,
                                        inter_w, denom, denom2,
                                        cursor_e, cursor_u, kg, ucsr, E, IE);

    // ---- hops ----
    size_t waves = (size_t)n_ent + n_users;
    int gb = (int)((waves * 64 + 255) / 256);

    // hop 1: src=ent0b -> ent_a;  usr_res = user_emb + y
    k_hop<<<gb, 256, 0, stream>>>(offs_e, counts_e, kg, offs_u, counts_u, ucsr,
                                  denom2, rel_emb, ent0b, ent0b, ent_a, ent_b,
                                  ent_a, ent_res, user_emb, usr_res,
                                  n_ent, n_users, 1);
    // hop 2: src=ent_a -> ent_b;  usr_res += y
    k_hop<<<gb, 256, 0, stream>>>(offs_e, counts_e, kg, offs_u, counts_u, ucsr,
                                  denom2, rel_emb, ent_a, ent0b, ent_a, ent_b,
                                  ent_b, ent_res, user_emb, usr_res,
                                  n_ent, n_users, 2);
    // hop 3: src=ent_b; ent_res = ent0 + y1 + y2 + y (eta);  usr_res += y
    k_hop<<<gb, 256, 0, stream>>>(offs_e, counts_e, kg, offs_u, counts_u, ucsr,
                                  denom2, rel_emb, ent_b, ent0b, ent_a, ent_b,
                                  ent_b /*unused*/, ent_res, user_emb, usr_res,
                                  n_ent, n_users, 3);
}